// Round 4
// baseline (7638.118 us; speedup 1.0000x reference)
//
#include <hip/hip_runtime.h>

// HighwayLayerDiscrete: 256-step recurrent highway net, batch 64, units 1024.
// Phase P = t*4+p: p0: h=lrelu(y@w_y + xproj[t]); p1/p2: h=lrelu(h@w_h[l]+b_h[l]);
// p3: y += h@w_out + b_out; out[:,t,:]=y.
//
// R11 = R10 resubmitted (R10 never ran: container was wedged by R9's
// deadlock) + BOUNDED POLL so any sync bug => fast wrong-answer, never a
// wedged container. Changes vs R7 base (proven 6.44 ms):
//  1. __launch_bounds__(512) (no min-waves): grid is 256 WGs on 256 CUs =
//     1 WG/CU ALWAYS, so R7's (512,2) VGPR cap bought nothing and forced the
//     compiler to sink the W prefetch into compute (VGPR_Count=104 < 128
//     needed by wreg[32]). Cap now 256.
//  2. TRUE W PREFETCH: volatile-asm b128 loads (cannot be sunk/split),
//     left in flight across flagpost/poll/stage; drained by explicit
//     s_waitcnt vmcnt(0) + sched_barrier(0) before compute (rule 18).
//  3. PER-PRODUCER FLAG STORES replace the single fetch_add (32 serialized
//     far-atomic RMWs on one LLC line per phase). Release chain unchanged:
//     waitcnt0 + barrier + relaxed agent store of P+1. Acquire: wave0's 32
//     lanes read all 32 flags as ONE coalesced 128B LLC load, __all(f>=P),
//     BOUNDED at 2^17 iters (~40ms) -> bail (wrong data, fast fail).
//  + red2 de-aliased from a_s (passed in R8): drops the compute->red barrier.
// R8 post-mortem: per-wave poll + scattered 128B staging = regression (7.16).
// R9 post-mortem: sc0 "XCD-L2-coherent" exchange DEADLOCKED (sc0 load can hit
// stale L1) -- no unproven coherence tiers, ever. All cross-WG traffic stays
// on the proven sc1/LLC path.
// Carried invariants: 256 coop blocks x 512 thr (R4: >256 silently fails);
// no cross-WG split-K (R2/R3); no fences ever (R1: wbl2/inv = 66 ms);
// release = waitcnt0 + barrier + flag store; acquire = poll + barrier +
// asm clobber; LDS skew injective (R5).

constexpr int B = 64, T = 256, U = 1024, E = 512;
constexpr int BU = B * U;     // 65536
constexpr int APITCH = 1156;  // A-row pitch (1024 + 36-skew; ==4 mod 8)
constexpr int RPITCH = 264;   // red2 per-s pitch

#define LRELU(v) ((v) > 0.f ? (v) : 0.2f * (v))

using f4 = float __attribute__((ext_vector_type(4)));

__device__ __forceinline__ unsigned long long llc_load64(const float* p) {
  return __hip_atomic_load((const unsigned long long*)p, __ATOMIC_RELAXED,
                           __HIP_MEMORY_SCOPE_AGENT);
}
__device__ __forceinline__ void llc_store(float* p, float v) {
  __hip_atomic_store(p, v, __ATOMIC_RELAXED, __HIP_MEMORY_SCOPE_AGENT);
}
__device__ __forceinline__ unsigned llc_flag(const unsigned* p) {
  return __hip_atomic_load(p, __ATOMIC_RELAXED, __HIP_MEMORY_SCOPE_AGENT);
}
__device__ __forceinline__ void llc_flag_store(unsigned* p, unsigned v) {
  __hip_atomic_store(p, v, __ATOMIC_RELAXED, __HIP_MEMORY_SCOPE_AGENT);
}

// 32x b128 W loads, NO waitcnt: left in flight on purpose (W is read-only
// constant data; no ordering needed vs anything). Drained explicitly before
// the consuming FMAs.
__device__ __forceinline__ void wprefetch(const float* wp, f4* wr) {
#pragma unroll
  for (int blk = 0; blk < 4; ++blk) {
    const float* q0 = wp + (size_t)(8 * blk + 0) * U;
    const float* q1 = wp + (size_t)(8 * blk + 1) * U;
    const float* q2 = wp + (size_t)(8 * blk + 2) * U;
    const float* q3 = wp + (size_t)(8 * blk + 3) * U;
    const float* q4 = wp + (size_t)(8 * blk + 4) * U;
    const float* q5 = wp + (size_t)(8 * blk + 5) * U;
    const float* q6 = wp + (size_t)(8 * blk + 6) * U;
    const float* q7 = wp + (size_t)(8 * blk + 7) * U;
    asm volatile(
        "global_load_dwordx4 %0, %8, off\n\t"
        "global_load_dwordx4 %1, %9, off\n\t"
        "global_load_dwordx4 %2, %10, off\n\t"
        "global_load_dwordx4 %3, %11, off\n\t"
        "global_load_dwordx4 %4, %12, off\n\t"
        "global_load_dwordx4 %5, %13, off\n\t"
        "global_load_dwordx4 %6, %14, off\n\t"
        "global_load_dwordx4 %7, %15, off"
        : "=&v"(wr[8 * blk + 0]), "=&v"(wr[8 * blk + 1]),
          "=&v"(wr[8 * blk + 2]), "=&v"(wr[8 * blk + 3]),
          "=&v"(wr[8 * blk + 4]), "=&v"(wr[8 * blk + 5]),
          "=&v"(wr[8 * blk + 6]), "=&v"(wr[8 * blk + 7])
        : "v"(q0), "v"(q1), "v"(q2), "v"(q3), "v"(q4), "v"(q5), "v"(q6),
          "v"(q7));
  }
}

// ---------------- init: zero flags, y0 into slot1 and ybuf ----------------
__global__ void k_init(float* __restrict__ slot1, float* __restrict__ ybuf,
                       const float* __restrict__ h0,
                       unsigned* __restrict__ flags) {
  int tid = blockIdx.x * 256 + threadIdx.x;
  if (tid < 512) flags[tid] = 0u;
  if (tid < BU) {
    float v = h0[tid & (U - 1)];
    slot1[tid] = v;
    ybuf[tid] = v;
  }
}

// ------- xproj[t*64+n][u] = emb[x[n][t]] @ w_x + b_in (R2/R3-proven) -------
__global__ __launch_bounds__(256) void k_xproj(
    const int* __restrict__ x, const float* __restrict__ emb,
    const float* __restrict__ w_x, const float* __restrict__ b_in,
    float* __restrict__ xp) {
  __shared__ float a_s[64][36];
  __shared__ float w_s[32][64];
  __shared__ int idxs[64];
  const int tid = threadIdx.x;
  const int m0 = blockIdx.x * 64;
  const int c0 = blockIdx.y * 64;
  if (tid < 64) {
    int m = m0 + tid;
    idxs[tid] = x[(m & 63) * T + (m >> 6)];  // x[n][t], row m = t*64+n
  }
  __syncthreads();
  const int rq = tid >> 4, cq = tid & 15;
  float acc[4][4] = {};
  for (int k0 = 0; k0 < E; k0 += 32) {
#pragma unroll
    for (int rep = 0; rep < 8; ++rep) {
      int e = rep * 256 + tid;
      int r = e >> 5, k = e & 31;
      a_s[r][k] = emb[(size_t)idxs[r] * E + k0 + k];
    }
#pragma unroll
    for (int rep = 0; rep < 2; ++rep) {
      int e = rep * 256 + tid;
      int kr = e >> 4, q = e & 15;
      *(float4*)&w_s[kr][4 * q] =
          *(const float4*)(w_x + (size_t)(k0 + kr) * U + c0 + 4 * q);
    }
    __syncthreads();
#pragma unroll
    for (int kc = 0; kc < 32; kc += 4) {
      float4 a4[4], w4[4];
#pragma unroll
      for (int i = 0; i < 4; ++i) a4[i] = *(const float4*)&a_s[4 * rq + i][kc];
#pragma unroll
      for (int kk = 0; kk < 4; ++kk)
        w4[kk] = *(const float4*)&w_s[kc + kk][4 * cq];
#pragma unroll
      for (int i = 0; i < 4; ++i) {
        const float av[4] = {a4[i].x, a4[i].y, a4[i].z, a4[i].w};
#pragma unroll
        for (int kk = 0; kk < 4; ++kk) {
          acc[i][0] += av[kk] * w4[kk].x;
          acc[i][1] += av[kk] * w4[kk].y;
          acc[i][2] += av[kk] * w4[kk].z;
          acc[i][3] += av[kk] * w4[kk].w;
        }
      }
    }
    __syncthreads();
  }
  const float4 bb = *(const float4*)(b_in + c0 + 4 * cq);
  const float bv[4] = {bb.x, bb.y, bb.z, bb.w};
#pragma unroll
  for (int i = 0; i < 4; ++i) {
    float4 o;
    o.x = acc[i][0] + bv[0];
    o.y = acc[i][1] + bv[1];
    o.z = acc[i][2] + bv[2];
    o.w = acc[i][3] + bv[3];
    *(float4*)(xp + (size_t)(m0 + 4 * rq + i) * U + c0 + 4 * cq) = o;
  }
}

// ---------------- sequential pipeline ----------------
// 256 WGs = 8 rg x 32 cg. Thread (s,ri,ci): K-slice [32s,32s+32), rows
// [4ri,4ri+4) of 8, cols [4ci,4ci+4) of 32. Partials -> red2[s][out] pitch
// 264 (separate buffer). Barriers/phase: poll, post-stage, post-red, drain.
__global__ __launch_bounds__(512) void k_seq(
    const float* __restrict__ xp, const float* __restrict__ w_y,
    const float* __restrict__ w_h, const float* __restrict__ b_h,
    const float* __restrict__ w_out, const float* __restrict__ b_out,
    float* __restrict__ out, float* __restrict__ slots,
    float* __restrict__ ybuf, unsigned* __restrict__ flags) {
  __shared__ float a_s[8 * APITCH];    // 9248 floats = 36992 B
  __shared__ float red2[32 * RPITCH];  // 8448 floats = 33792 B
  const int tid = threadIdx.x;
  const int cg = blockIdx.x & 31, rg = blockIdx.x >> 5;
  const int l = tid & 63;
  const int ci = l & 7, ri = (l >> 3) & 1;
  const int s = (tid >> 6) * 4 + ((l >> 4) & 3);
  const int cb = 4 * ci, r0 = 4 * ri, k0 = 32 * s;
  unsigned* const myflag = &flags[rg * 32 + cg];
  const unsigned* const pollf = &flags[rg * 32 + (l & 31)];

  // W base selector for phase P
  auto wbase = [&](int P) -> const float* {
    const int p = P & 3;
    const float* Wsrc = (p == 0)   ? w_y
                        : (p == 3) ? w_out
                                   : w_h + (size_t)(p - 1) * U * U;
    return Wsrc + (size_t)k0 * U + 32 * cg + cb;
  };
  // ---- forced W prefetch for P=0 (volatile asm: cannot be sunk) ----
  f4 wreg[32];  // 128 VGPRs, genuinely live across flagpost/poll/stage
  wprefetch(wbase(0), wreg);

  for (int P = 0; P < 4 * T; ++P) {
    const int t = P >> 2, p = P & 3;
    const float* Asrc =
        slots + (size_t)((P + 1) & 1) * BU + (size_t)(8 * rg) * U;
    float* slotw = slots + (size_t)(P & 1) * BU;
    // ---- 1. poll: wave0's 32 lanes read all 32 producer flags (128B).
    //      BOUNDED: if the protocol ever breaks, bail (=> wrong answer,
    //      fast fail) instead of wedging the container. ----
    if (P > 0) {
      if (tid < 64) {
        const unsigned tg = (unsigned)P;
        for (int it = 0; it < (1 << 17); ++it) {
          unsigned f = llc_flag(pollf);
          if (__all((int)(f >= tg))) break;
          __builtin_amdgcn_s_sleep(1);
        }
      }
      __syncthreads();
      asm volatile("" ::: "memory");
    }
    // ---- 2. stage A: 8 rows x 1024, cooperative, coalesced (R7 pattern) --
#pragma unroll
    for (int rep = 0; rep < 4; ++rep) {
      int idx4 = 512 * rep + tid;  // f4 index in [0,2048)
      int row = idx4 >> 8, kq = idx4 & 255, k = 4 * kq;
      const float* pa = Asrc + (size_t)row * U + k;
      unsigned long long v0 = llc_load64(pa);
      unsigned long long v1 = llc_load64(pa + 2);
      f4 v;
      ((unsigned long long*)&v)[0] = v0;
      ((unsigned long long*)&v)[1] = v1;
      *(f4*)&a_s[row * APITCH + 36 * (k >> 5) + (k & 31)] = v;
    }
    __syncthreads();
    // ---- 3. drain outstanding W prefetch, pin schedule, then compute ----
    asm volatile("s_waitcnt vmcnt(0)" ::: "memory");
    __builtin_amdgcn_sched_barrier(0);
    f4 acc[4];
#pragma unroll
    for (int i = 0; i < 4; ++i) acc[i] = (f4){0.f, 0.f, 0.f, 0.f};
    {
      const int abase = r0 * APITCH + 36 * s;
#pragma unroll
      for (int q = 0; q < 8; ++q) {
        const int ai = abase + 4 * q;
        f4 a0 = *(const f4*)&a_s[ai];
        f4 a1 = *(const f4*)&a_s[ai + APITCH];
        f4 a2 = *(const f4*)&a_s[ai + 2 * APITCH];
        f4 a3 = *(const f4*)&a_s[ai + 3 * APITCH];
        const f4 w0 = wreg[4 * q], w1 = wreg[4 * q + 1];
        const f4 w2 = wreg[4 * q + 2], w3 = wreg[4 * q + 3];
        acc[0] += a0.x * w0 + a0.y * w1 + a0.z * w2 + a0.w * w3;
        acc[1] += a1.x * w0 + a1.y * w1 + a1.z * w2 + a1.w * w3;
        acc[2] += a2.x * w0 + a2.y * w1 + a2.z * w2 + a2.w * w3;
        acc[3] += a3.x * w0 + a3.y * w1 + a3.z * w2 + a3.w * w3;
      }
    }
    // ---- 4. write partials red2[s*264 + out] (de-aliased: no pre-barrier) -
#pragma unroll
    for (int i = 0; i < 4; ++i)
      *(f4*)&red2[s * RPITCH + (r0 + i) * 32 + cb] = acc[i];
    __syncthreads();  // B1: all partials visible
    // ---- 5. finalize: 256 threads, sum 32 partials, bias+act, store ----
    if (tid < 256) {
      float sum = 0.f;
#pragma unroll
      for (int z = 0; z < 32; ++z) sum += red2[z * RPITCH + tid];
      const int row = 8 * rg + (tid >> 5);
      const int u = 32 * cg + (tid & 31);
      if (p == 0) {
        float v = sum + xp[((size_t)t * B + row) * U + u];
        llc_store(slotw + (size_t)row * U + u, LRELU(v));
      } else if (p < 3) {
        float v = sum + b_h[(p - 1) * U + u];
        llc_store(slotw + (size_t)row * U + u, LRELU(v));
      } else {
        const size_t yi = (size_t)row * U + u;
        float yn = ybuf[yi] + sum + b_out[u];  // WG-private: plain ok
        ybuf[yi] = yn;
        out[((size_t)row * T + t) * U + u] = yn;
        llc_store(slotw + yi, yn);  // y is next p0's A
      }
    }
    // ---- 6. drain: all stores at LLC before flag post ----
    asm volatile("" ::: "memory");
    __builtin_amdgcn_s_waitcnt(0);
    __syncthreads();  // B2: red2 reads also done before next phase
    // ---- 7. W prefetch for P+1 (in flight across flagpost/poll/stage) ----
    if (P < 4 * T - 1) wprefetch(wbase(P + 1), wreg);
    asm volatile("" ::: "memory");
    if (tid == 0) llc_flag_store(myflag, (unsigned)(P + 1));
  }
}

extern "C" void kernel_launch(void* const* d_in, const int* in_sizes, int n_in,
                              void* d_out, int out_size, void* d_ws,
                              size_t ws_size, hipStream_t stream) {
  const int* x = (const int*)d_in[0];
  const float* emb = (const float*)d_in[1];
  const float* w_y = (const float*)d_in[2];
  const float* w_x = (const float*)d_in[3];
  const float* b_in = (const float*)d_in[4];
  const float* w_h = (const float*)d_in[5];
  const float* b_h = (const float*)d_in[6];
  const float* w_out = (const float*)d_in[7];
  const float* b_out = (const float*)d_in[8];
  const float* h0 = (const float*)d_in[9];
  float* out = (float*)d_out;

  // workspace (floats): xproj | slots[2] | ybuf | flags
  float* ws = (float*)d_ws;
  float* xpb = ws;                         // T*B*U
  float* slots = xpb + (size_t)T * B * U;  // 2*BU
  float* ybuf = slots + 2 * (size_t)BU;    // BU
  unsigned* flags = (unsigned*)(ybuf + (size_t)BU);  // 256 uints (512 zeroed)

  k_init<<<256, 256, 0, stream>>>(slots + (size_t)BU, ybuf, h0, flags);
  dim3 g1(256, 16);
  k_xproj<<<g1, 256, 0, stream>>>(x, emb, w_x, b_in, xpb);

  void* args[] = {&xpb,   &w_y, &w_h,   &b_h,  &w_out,
                  &b_out, &out, &slots, &ybuf, &flags};
  hipLaunchCooperativeKernel((void*)k_seq, dim3(256), dim3(512), args, 0u,
                             stream);
}

// Round 5
// 6966.932 us; speedup vs baseline: 1.0963x; 1.0963x over previous
//
#include <hip/hip_runtime.h>

// HighwayLayerDiscrete: 256-step recurrent highway net, batch 64, units 1024.
// Phase P = t*4+p: p0: h=lrelu(y@w_y + xproj[t]); p1/p2: h=lrelu(h@w_h[l]+b_h[l]);
// p3: y += h@w_out + b_out; out[:,t,:]=y.
//
// R12 = R7 VERBATIM (proven 6.44 ms) + three local edits, nothing structural:
//  1. CROSS-LANE PRE-REDUCTION: the 4 K-slices of one wave (s=4w+sub,
//     sub=lane bits 4-5) butterfly-reduce via __shfl_xor(16/32) in registers
//     -> partials per output 32->8. red2 writes drop 4x (512 b128), finalize
//     reads drop 32->8 per thread. Trades LDS/barrier-path time for VALU
//     (which is only ~24% busy).
//  2. p3 OUT-STORE DEFERRED past the flag post: out[] is read by nobody
//     in-kernel, but R7 drained its HBM store before releasing the flag.
//     Now stored after; next phase's waitcnt(0) absorbs it for free.
//  3. BOUNDED POLL (2^20 iters): protocol bug => fast wrong answer, never a
//     wedged container (R9 lesson). Zero cost on the correct path.
// R8/R11 post-mortems: per-wave poll+scattered stage (R8, 7.16) and forced
// asm W-prefetch + per-producer flags (R11, 7.64) BOTH regressed R7 while
// VALUBusy dropped -- restructures add stall, not overlap; VGPR_Count stayed
// 104 so the "128-VGPR wreg residency" never materializes. Compiler's
// schedule of R7's simple form wins; only local edits from here.
// R9 post-mortem: sc0 exchange deadlocked -- no unproven coherence tiers.
// Carried invariants: 256 coop blocks x 512 thr (R4: >256 silently fails);
// no cross-WG split-K (R2/R3); no fences ever (R1: wbl2/inv = 66 ms);
// cross-WG data via relaxed agent-scope atomics (sc1 at LLC); release =
// waitcnt0+barrier+flag; acquire = tid0 poll + barrier + asm clobber;
// LDS skew injective (R5); a_s/red2 alias ordered by barriers (R7).

constexpr int B = 64, T = 256, U = 1024, E = 512;
constexpr int BU = B * U;     // 65536
constexpr int APITCH = 1156;  // A-row pitch (1024 + 36-skew; ==4 mod 8)

#define LRELU(v) ((v) > 0.f ? (v) : 0.2f * (v))

using f4 = float __attribute__((ext_vector_type(4)));

__device__ __forceinline__ unsigned long long llc_load64(const float* p) {
  return __hip_atomic_load((const unsigned long long*)p, __ATOMIC_RELAXED,
                           __HIP_MEMORY_SCOPE_AGENT);
}
__device__ __forceinline__ void llc_store(float* p, float v) {
  __hip_atomic_store(p, v, __ATOMIC_RELAXED, __HIP_MEMORY_SCOPE_AGENT);
}
__device__ __forceinline__ unsigned llc_flag(const unsigned* p) {
  return __hip_atomic_load(p, __ATOMIC_RELAXED, __HIP_MEMORY_SCOPE_AGENT);
}
__device__ __forceinline__ f4 shflx(f4 v, int m) {
  f4 r;
  r.x = __shfl_xor(v.x, m);
  r.y = __shfl_xor(v.y, m);
  r.z = __shfl_xor(v.z, m);
  r.w = __shfl_xor(v.w, m);
  return r;
}

// ---------------- init: zero flags, y0 into slot1 and ybuf ----------------
__global__ void k_init(float* __restrict__ slot1, float* __restrict__ ybuf,
                       const float* __restrict__ h0,
                       unsigned* __restrict__ flags) {
  int tid = blockIdx.x * 256 + threadIdx.x;
  if (tid < 512) flags[tid] = 0u;
  if (tid < BU) {
    float v = h0[tid & (U - 1)];
    slot1[tid] = v;
    ybuf[tid] = v;
  }
}

// ------- xproj[t*64+n][u] = emb[x[n][t]] @ w_x + b_in (R2/R3-proven) -------
__global__ __launch_bounds__(256) void k_xproj(
    const int* __restrict__ x, const float* __restrict__ emb,
    const float* __restrict__ w_x, const float* __restrict__ b_in,
    float* __restrict__ xp) {
  __shared__ float a_s[64][36];
  __shared__ float w_s[32][64];
  __shared__ int idxs[64];
  const int tid = threadIdx.x;
  const int m0 = blockIdx.x * 64;
  const int c0 = blockIdx.y * 64;
  if (tid < 64) {
    int m = m0 + tid;
    idxs[tid] = x[(m & 63) * T + (m >> 6)];  // x[n][t], row m = t*64+n
  }
  __syncthreads();
  const int rq = tid >> 4, cq = tid & 15;
  float acc[4][4] = {};
  for (int k0 = 0; k0 < E; k0 += 32) {
#pragma unroll
    for (int rep = 0; rep < 8; ++rep) {
      int e = rep * 256 + tid;
      int r = e >> 5, k = e & 31;
      a_s[r][k] = emb[(size_t)idxs[r] * E + k0 + k];
    }
#pragma unroll
    for (int rep = 0; rep < 2; ++rep) {
      int e = rep * 256 + tid;
      int kr = e >> 4, q = e & 15;
      *(float4*)&w_s[kr][4 * q] =
          *(const float4*)(w_x + (size_t)(k0 + kr) * U + c0 + 4 * q);
    }
    __syncthreads();
#pragma unroll
    for (int kc = 0; kc < 32; kc += 4) {
      float4 a4[4], w4[4];
#pragma unroll
      for (int i = 0; i < 4; ++i) a4[i] = *(const float4*)&a_s[4 * rq + i][kc];
#pragma unroll
      for (int kk = 0; kk < 4; ++kk)
        w4[kk] = *(const float4*)&w_s[kc + kk][4 * cq];
#pragma unroll
      for (int i = 0; i < 4; ++i) {
        const float av[4] = {a4[i].x, a4[i].y, a4[i].z, a4[i].w};
#pragma unroll
        for (int kk = 0; kk < 4; ++kk) {
          acc[i][0] += av[kk] * w4[kk].x;
          acc[i][1] += av[kk] * w4[kk].y;
          acc[i][2] += av[kk] * w4[kk].z;
          acc[i][3] += av[kk] * w4[kk].w;
        }
      }
    }
    __syncthreads();
  }
  const float4 bb = *(const float4*)(b_in + c0 + 4 * cq);
  const float bv[4] = {bb.x, bb.y, bb.z, bb.w};
#pragma unroll
  for (int i = 0; i < 4; ++i) {
    float4 o;
    o.x = acc[i][0] + bv[0];
    o.y = acc[i][1] + bv[1];
    o.z = acc[i][2] + bv[2];
    o.w = acc[i][3] + bv[3];
    *(float4*)(xp + (size_t)(m0 + 4 * rq + i) * U + c0 + 4 * cq) = o;
  }
}

// ---------------- sequential pipeline ----------------
// 256 WGs = 8 rg x 32 cg (XCD = cg&7, L2-affine: per-XCD W working set is
// 4 panels x 4 matrices = 2 MB, fits 4 MB L2). Thread (s,ri,ci): K-slice
// [32s,32s+32), rows [4ri,4ri+4) of 8, cols [4ci,4ci+4) of 32. Partials
// pre-reduced in-wave (shfl_xor over s-bits) -> red2[w][out] pitch 264,
// w = wave id (8 rows). a_s (8 x 1156 = 9248 floats) ALIASES red2 (8 x 264
// = 2112) — barriers order A-read < red-write < red-read < next A-write.
__global__ __launch_bounds__(512, 2) void k_seq(
    const float* __restrict__ xp, const float* __restrict__ w_y,
    const float* __restrict__ w_h, const float* __restrict__ b_h,
    const float* __restrict__ w_out, const float* __restrict__ b_out,
    float* __restrict__ out, float* __restrict__ slots,
    float* __restrict__ ybuf, unsigned* __restrict__ flags) {
  __shared__ float smem[8 * APITCH];  // 9248 floats = 36992 B
  float* const a_s = smem;   // [row][36*(k>>5) + (k&31)] (injective skew)
  float* const red2 = smem;  // [w][out], pitch 264 (alias — see barriers)
  const int tid = threadIdx.x;
  const int cg = blockIdx.x & 31, rg = blockIdx.x >> 5;
  const int l = tid & 63;
  const int ci = l & 7, ri = (l >> 3) & 1;
  const int w = tid >> 6;                 // wave id 0..7
  const int s = w * 4 + ((l >> 4) & 3);   // K-slice
  const int cb = 4 * ci, r0 = 4 * ri, k0 = 32 * s;

  // W base selector for phase P
  auto wbase = [&](int P) -> const float* {
    const int p = P & 3;
    const float* Wsrc = (p == 0)   ? w_y
                        : (p == 3) ? w_out
                                   : w_h + (size_t)(p - 1) * U * U;
    return Wsrc + (size_t)k0 * U + 32 * cg + cb;
  };
  // ---- W prefetch for P=0 (static addresses -> latency off critical path) --
  f4 wreg[32];  // W[k0+j][cb..cb+4), j=0..31
  {
    const float* wp = wbase(0);
#pragma unroll
    for (int j = 0; j < 32; ++j) wreg[j] = *(const f4*)(wp + (size_t)j * U);
  }

  for (int P = 0; P < 4 * T; ++P) {
    const int t = P >> 2, p = P & 3;
    const float* Asrc =
        slots + (size_t)((P + 1) & 1) * BU + (size_t)(8 * rg) * U;
    float* slotw = slots + (size_t)(P & 1) * BU;
    float yout = 0.f;       // deferred p3 out-store
    size_t oidx = 0;
    int do_out = 0;
    // ---- 1. poll flag[rg] (tid0, s_sleep backoff, BOUNDED for safety) ----
    if (P > 0) {
      if (tid == 0) {
        const unsigned tg = 32u * (unsigned)P;
        for (int it = 0; it < (1 << 20); ++it) {
          if (llc_flag(&flags[rg * 32]) >= tg) break;
          __builtin_amdgcn_s_sleep(1);
        }
      }
      __syncthreads();
      asm volatile("" ::: "memory");
    }
    // ---- 2. stage A: 8 rows x 1024, 8B sc1 loads -> single b128 LDS write --
#pragma unroll
    for (int rep = 0; rep < 4; ++rep) {
      int idx4 = 512 * rep + tid;  // f4 index in [0,2048)
      int row = idx4 >> 8, kq = idx4 & 255, k = 4 * kq;
      const float* pa = Asrc + (size_t)row * U + k;
      unsigned long long v0 = llc_load64(pa);
      unsigned long long v1 = llc_load64(pa + 2);
      f4 v;
      ((unsigned long long*)&v)[0] = v0;
      ((unsigned long long*)&v)[1] = v1;
      *(f4*)&a_s[row * APITCH + 36 * (k >> 5) + (k & 31)] = v;
    }
    __syncthreads();
    // ---- 3. main: 4x4x(K=32) tile; A from LDS, W from registers ----
    f4 acc[4];
#pragma unroll
    for (int i = 0; i < 4; ++i) acc[i] = (f4){0.f, 0.f, 0.f, 0.f};
    {
      const int abase = r0 * APITCH + 36 * s;  // 36*(k0>>5) = 36s
#pragma unroll
      for (int q = 0; q < 8; ++q) {
        const int ai = abase + 4 * q;
        f4 a0 = *(const f4*)&a_s[ai];
        f4 a1 = *(const f4*)&a_s[ai + APITCH];
        f4 a2 = *(const f4*)&a_s[ai + 2 * APITCH];
        f4 a3 = *(const f4*)&a_s[ai + 3 * APITCH];
        const f4 w0 = wreg[4 * q], w1 = wreg[4 * q + 1];
        const f4 w2 = wreg[4 * q + 2], w3 = wreg[4 * q + 3];
        acc[0] += a0.x * w0 + a0.y * w1 + a0.z * w2 + a0.w * w3;
        acc[1] += a1.x * w0 + a1.y * w1 + a1.z * w2 + a1.w * w3;
        acc[2] += a2.x * w0 + a2.y * w1 + a2.z * w2 + a2.w * w3;
        acc[3] += a3.x * w0 + a3.y * w1 + a3.z * w2 + a3.w * w3;
      }
    }
    // ---- 3b. in-wave pre-reduction over the wave's 4 K-slices ----
    //      (lanes l^16, l^32 hold the same (ri,ci) for s=4w..4w+3;
    //       after the butterfly every lane holds the wave-local sum)
#pragma unroll
    for (int i = 0; i < 4; ++i) {
      acc[i] += shflx(acc[i], 16);
      acc[i] += shflx(acc[i], 32);
    }
    __syncthreads();  // all a_s reads done -> safe to alias-write red2
    // ---- 4. write partials red2[w*264 + out], b128, sub==0 lanes only ----
    if (((l >> 4) & 3) == 0) {
#pragma unroll
      for (int i = 0; i < 4; ++i)
        *(f4*)&red2[w * 264 + (r0 + i) * 32 + cb] = acc[i];
    }
    __syncthreads();
    // ---- 5. finalize: 256 threads, sum 8 wave-partials, bias+act, store ---
    if (tid < 256) {
      float sum = 0.f;
#pragma unroll
      for (int z = 0; z < 8; ++z) sum += red2[z * 264 + tid];
      const int row = 8 * rg + (tid >> 5);
      const int u = 32 * cg + (tid & 31);
      if (p == 0) {
        float v = sum + xp[((size_t)t * B + row) * U + u];
        llc_store(slotw + (size_t)row * U + u, LRELU(v));
      } else if (p < 3) {
        float v = sum + b_h[(p - 1) * U + u];
        llc_store(slotw + (size_t)row * U + u, LRELU(v));
      } else {
        const size_t yi = (size_t)row * U + u;
        float yn = ybuf[yi] + sum + b_out[u];  // WG-private: plain ok
        ybuf[yi] = yn;
        llc_store(slotw + yi, yn);  // y is next p0's A
        yout = yn;                  // out[] store deferred past flag post
        oidx = ((size_t)row * T + t) * U + u;
        do_out = 1;
      }
    }
    // ---- 6. drain: exchange stores at LLC before the flag post ----
    asm volatile("" ::: "memory");
    __builtin_amdgcn_s_waitcnt(0);
    __syncthreads();
    // ---- 7. W prefetch for P+1 (issued BEFORE the flag post so the L2/HBM
    //         W traffic overlaps post + poll + A-stage of the next phase) ----
    if (P < 4 * T - 1) {
      const float* wp = wbase(P + 1);
#pragma unroll
      for (int j = 0; j < 32; ++j) wreg[j] = *(const f4*)(wp + (size_t)j * U);
    }
    if (tid == 0)
      __hip_atomic_fetch_add(&flags[rg * 32], 1u, __ATOMIC_RELAXED,
                             __HIP_MEMORY_SCOPE_AGENT);
    // ---- 8. deferred p3 out-store (HBM latency off the flag critical path;
    //         next phase's waitcnt(0) absorbs it) ----
    if (do_out) out[oidx] = yout;
  }
}

extern "C" void kernel_launch(void* const* d_in, const int* in_sizes, int n_in,
                              void* d_out, int out_size, void* d_ws,
                              size_t ws_size, hipStream_t stream) {
  const int* x = (const int*)d_in[0];
  const float* emb = (const float*)d_in[1];
  const float* w_y = (const float*)d_in[2];
  const float* w_x = (const float*)d_in[3];
  const float* b_in = (const float*)d_in[4];
  const float* w_h = (const float*)d_in[5];
  const float* b_h = (const float*)d_in[6];
  const float* w_out = (const float*)d_in[7];
  const float* b_out = (const float*)d_in[8];
  const float* h0 = (const float*)d_in[9];
  float* out = (float*)d_out;

  // workspace (floats): xproj | slots[2] | ybuf | flags
  float* ws = (float*)d_ws;
  float* xpb = ws;                         // T*B*U
  float* slots = xpb + (size_t)T * B * U;  // 2*BU
  float* ybuf = slots + 2 * (size_t)BU;    // BU
  unsigned* flags = (unsigned*)(ybuf + (size_t)BU);  // 512 uints

  k_init<<<256, 256, 0, stream>>>(slots + (size_t)BU, ybuf, h0, flags);
  dim3 g1(256, 16);
  k_xproj<<<g1, 256, 0, stream>>>(x, emb, w_x, b_in, xpb);

  void* args[] = {&xpb,   &w_y, &w_h,   &b_h,  &w_out,
                  &b_out, &out, &slots, &ybuf, &flags};
  hipLaunchCooperativeKernel((void*)k_seq, dim3(256), dim3(512), args, 0u,
                             stream);
}

// Round 6
// 6226.503 us; speedup vs baseline: 1.2267x; 1.1189x over previous
//
#include <hip/hip_runtime.h>

// HighwayLayerDiscrete: 256-step recurrent highway net, batch 64, units 1024.
// Phase P = t*4+p: p0: h=lrelu(y@w_y + xproj[t]); p1/p2: h=lrelu(h@w_h[l]+b_h[l]);
// p3: y += h@w_out + b_out; out[:,t,:]=y.
//
// R13 = R7 BYTE-FOR-BYTE (proven 6.44 ms) except four pure latency removals
// on the release/acquire chain. No new cross-lane ops (R12 lesson: shfl
// chains cost more than pipelined LDS reads), no asm loads (R11 lesson:
// forced wreg residency spills to scratch), no stage restructure (R8 lesson).
//  1. PER-PRODUCER FLAG STORE: tid0 stores flags[rg*32+cg]=P+1 (relaxed,
//     agent) instead of 32 WGs fetch_add-ing ONE LLC line (serialized RMWs;
//     consumer waits for the LAST). Acquire: wave0's 32 lanes read the 32
//     flags as ONE coalesced 128B LLC load, __all(f>=P), bounded 2^20.
//  2. xpre/ypre PREFETCH: finalize's p0 xp-load and p3 ybuf-load were issued
//     AFTER the reduction sum -> ~600cy L2/LLC latency on the release chain.
//     Both are phase-start-known (xp precomputed, ybuf WG-private) and
//     loop-invariant addresses; now loaded before the poll, hidden under
//     poll+stage.
//  3. p3 OUT-STORE DEFERRED past the flag post (nobody reads out[] in-kernel;
//     next phase's waitcnt(0) absorbs the ack).
//  4. BOUNDED POLL: protocol bug => fast wrong answer, never a wedged
//     container (R9 lesson). Zero cost on the correct path.
// Post-mortems: R8 per-wave poll+scattered stage 7.16; R11 asm W-prefetch
// (scratch spill, SGPR 48->112) + flags 7.64 (confounded); R12 shfl
// pre-reduction 6.97. R7 structure is a local optimum; only the exchange
// protocol remained untested in isolation -- that is this round.
// Carried invariants: 256 coop blocks x 512 thr (R4: >256 silently fails);
// no cross-WG split-K (R2/R3); no fences ever (R1: wbl2/inv = 66 ms);
// cross-WG data via relaxed agent-scope atomics (sc1 at LLC); release =
// waitcnt0+barrier+flag store; acquire = coalesced poll + barrier + asm
// clobber; LDS skew injective (R5); a_s/red2 alias ordered by barriers.

constexpr int B = 64, T = 256, U = 1024, E = 512;
constexpr int BU = B * U;     // 65536
constexpr int APITCH = 1156;  // A-row pitch (1024 + 36-skew; ==4 mod 8)

#define LRELU(v) ((v) > 0.f ? (v) : 0.2f * (v))

using f4 = float __attribute__((ext_vector_type(4)));

__device__ __forceinline__ unsigned long long llc_load64(const float* p) {
  return __hip_atomic_load((const unsigned long long*)p, __ATOMIC_RELAXED,
                           __HIP_MEMORY_SCOPE_AGENT);
}
__device__ __forceinline__ void llc_store(float* p, float v) {
  __hip_atomic_store(p, v, __ATOMIC_RELAXED, __HIP_MEMORY_SCOPE_AGENT);
}
__device__ __forceinline__ unsigned llc_flag(const unsigned* p) {
  return __hip_atomic_load(p, __ATOMIC_RELAXED, __HIP_MEMORY_SCOPE_AGENT);
}
__device__ __forceinline__ void llc_flag_store(unsigned* p, unsigned v) {
  __hip_atomic_store(p, v, __ATOMIC_RELAXED, __HIP_MEMORY_SCOPE_AGENT);
}

// ---------------- init: zero flags, y0 into slot1 and ybuf ----------------
__global__ void k_init(float* __restrict__ slot1, float* __restrict__ ybuf,
                       const float* __restrict__ h0,
                       unsigned* __restrict__ flags) {
  int tid = blockIdx.x * 256 + threadIdx.x;
  if (tid < 512) flags[tid] = 0u;
  if (tid < BU) {
    float v = h0[tid & (U - 1)];
    slot1[tid] = v;
    ybuf[tid] = v;
  }
}

// ------- xproj[t*64+n][u] = emb[x[n][t]] @ w_x + b_in (R2/R3-proven) -------
__global__ __launch_bounds__(256) void k_xproj(
    const int* __restrict__ x, const float* __restrict__ emb,
    const float* __restrict__ w_x, const float* __restrict__ b_in,
    float* __restrict__ xp) {
  __shared__ float a_s[64][36];
  __shared__ float w_s[32][64];
  __shared__ int idxs[64];
  const int tid = threadIdx.x;
  const int m0 = blockIdx.x * 64;
  const int c0 = blockIdx.y * 64;
  if (tid < 64) {
    int m = m0 + tid;
    idxs[tid] = x[(m & 63) * T + (m >> 6)];  // x[n][t], row m = t*64+n
  }
  __syncthreads();
  const int rq = tid >> 4, cq = tid & 15;
  float acc[4][4] = {};
  for (int k0 = 0; k0 < E; k0 += 32) {
#pragma unroll
    for (int rep = 0; rep < 8; ++rep) {
      int e = rep * 256 + tid;
      int r = e >> 5, k = e & 31;
      a_s[r][k] = emb[(size_t)idxs[r] * E + k0 + k];
    }
#pragma unroll
    for (int rep = 0; rep < 2; ++rep) {
      int e = rep * 256 + tid;
      int kr = e >> 4, q = e & 15;
      *(float4*)&w_s[kr][4 * q] =
          *(const float4*)(w_x + (size_t)(k0 + kr) * U + c0 + 4 * q);
    }
    __syncthreads();
#pragma unroll
    for (int kc = 0; kc < 32; kc += 4) {
      float4 a4[4], w4[4];
#pragma unroll
      for (int i = 0; i < 4; ++i) a4[i] = *(const float4*)&a_s[4 * rq + i][kc];
#pragma unroll
      for (int kk = 0; kk < 4; ++kk)
        w4[kk] = *(const float4*)&w_s[kc + kk][4 * cq];
#pragma unroll
      for (int i = 0; i < 4; ++i) {
        const float av[4] = {a4[i].x, a4[i].y, a4[i].z, a4[i].w};
#pragma unroll
        for (int kk = 0; kk < 4; ++kk) {
          acc[i][0] += av[kk] * w4[kk].x;
          acc[i][1] += av[kk] * w4[kk].y;
          acc[i][2] += av[kk] * w4[kk].z;
          acc[i][3] += av[kk] * w4[kk].w;
        }
      }
    }
    __syncthreads();
  }
  const float4 bb = *(const float4*)(b_in + c0 + 4 * cq);
  const float bv[4] = {bb.x, bb.y, bb.z, bb.w};
#pragma unroll
  for (int i = 0; i < 4; ++i) {
    float4 o;
    o.x = acc[i][0] + bv[0];
    o.y = acc[i][1] + bv[1];
    o.z = acc[i][2] + bv[2];
    o.w = acc[i][3] + bv[3];
    *(float4*)(xp + (size_t)(m0 + 4 * rq + i) * U + c0 + 4 * cq) = o;
  }
}

// ---------------- sequential pipeline ----------------
// 256 WGs = 8 rg x 32 cg (XCD = cg&7, L2-affine). Thread (s,ri,ci): K-slice
// [32s,32s+32), rows [4ri,4ri+4) of 8, cols [4ci,4ci+4) of 32. Partials ->
// red2[s][out] pitch 264. a_s (8 x 1156 = 9248 floats) ALIASES red2 (32 x
// 264 = 8448) — barriers order A-read < red-write < red-read < next A-write.
__global__ __launch_bounds__(512, 2) void k_seq(
    const float* __restrict__ xp, const float* __restrict__ w_y,
    const float* __restrict__ w_h, const float* __restrict__ b_h,
    const float* __restrict__ w_out, const float* __restrict__ b_out,
    float* __restrict__ out, float* __restrict__ slots,
    float* __restrict__ ybuf, unsigned* __restrict__ flags) {
  __shared__ float smem[8 * APITCH];  // 9248 floats = 36992 B
  float* const a_s = smem;   // [row][36*(k>>5) + (k&31)] (injective skew)
  float* const red2 = smem;  // [s][out], pitch 264 (alias — see barriers)
  const int tid = threadIdx.x;
  const int cg = blockIdx.x & 31, rg = blockIdx.x >> 5;
  const int l = tid & 63;
  const int ci = l & 7, ri = (l >> 3) & 1;
  const int s = (tid >> 6) * 4 + ((l >> 4) & 3);
  const int cb = 4 * ci, r0 = 4 * ri, k0 = 32 * s;
  unsigned* const myflag = &flags[rg * 32 + cg];
  const unsigned* const pollf = &flags[rg * 32 + (l & 31)];
  // finalize coordinates (loop-invariant; valid for tid<256)
  const int frow = 8 * rg + (tid >> 5);
  const int fu = 32 * cg + (tid & 31);
  const size_t fyi = (size_t)frow * U + fu;

  // W base selector for phase P
  auto wbase = [&](int P) -> const float* {
    const int p = P & 3;
    const float* Wsrc = (p == 0)   ? w_y
                        : (p == 3) ? w_out
                                   : w_h + (size_t)(p - 1) * U * U;
    return Wsrc + (size_t)k0 * U + 32 * cg + cb;
  };
  // ---- W prefetch for P=0 (static addresses -> latency off critical path) --
  f4 wreg[32];  // W[k0+j][cb..cb+4), j=0..31
  {
    const float* wp = wbase(0);
#pragma unroll
    for (int j = 0; j < 32; ++j) wreg[j] = *(const f4*)(wp + (size_t)j * U);
  }

  for (int P = 0; P < 4 * T; ++P) {
    const int t = P >> 2, p = P & 3;
    const float* Asrc =
        slots + (size_t)((P + 1) & 1) * BU + (size_t)(8 * rg) * U;
    float* slotw = slots + (size_t)(P & 1) * BU;
    // ---- 0. finalize-operand prefetch (phase-start-known, WG-private /
    //         precomputed; latency hides under poll + stage) ----
    float xpre = 0.f, ypre = 0.f;
    if (tid < 256) {
      if (p == 0) xpre = xp[((size_t)t * B + frow) * U + fu];
      else if (p == 3) ypre = ybuf[fyi];
    }
    float yout = 0.f;  // deferred p3 out-store
    size_t oidx = 0;
    int do_out = 0;
    // ---- 1. acquire: wave0's 32 lanes read 32 producer flags (one 128B
    //         LLC transaction), __all(f>=P); bounded for container safety --
    if (P > 0) {
      if (tid < 64) {
        const unsigned tg = (unsigned)P;
        for (int it = 0; it < (1 << 20); ++it) {
          unsigned f = llc_flag(pollf);
          if (__all((int)(f >= tg))) break;
          __builtin_amdgcn_s_sleep(1);
        }
      }
      __syncthreads();
      asm volatile("" ::: "memory");
    }
    // ---- 2. stage A: 8 rows x 1024, 8B sc1 loads -> single b128 LDS write --
#pragma unroll
    for (int rep = 0; rep < 4; ++rep) {
      int idx4 = 512 * rep + tid;  // f4 index in [0,2048)
      int row = idx4 >> 8, kq = idx4 & 255, k = 4 * kq;
      const float* pa = Asrc + (size_t)row * U + k;
      unsigned long long v0 = llc_load64(pa);
      unsigned long long v1 = llc_load64(pa + 2);
      f4 v;
      ((unsigned long long*)&v)[0] = v0;
      ((unsigned long long*)&v)[1] = v1;
      *(f4*)&a_s[row * APITCH + 36 * (k >> 5) + (k & 31)] = v;
    }
    __syncthreads();
    // ---- 3. main: 4x4x(K=32) tile; A from LDS, W from registers ----
    f4 acc[4];
#pragma unroll
    for (int i = 0; i < 4; ++i) acc[i] = (f4){0.f, 0.f, 0.f, 0.f};
    {
      const int abase = r0 * APITCH + 36 * s;  // 36*(k0>>5) = 36s
#pragma unroll
      for (int q = 0; q < 8; ++q) {
        const int ai = abase + 4 * q;
        f4 a0 = *(const f4*)&a_s[ai];
        f4 a1 = *(const f4*)&a_s[ai + APITCH];
        f4 a2 = *(const f4*)&a_s[ai + 2 * APITCH];
        f4 a3 = *(const f4*)&a_s[ai + 3 * APITCH];
        const f4 w0 = wreg[4 * q], w1 = wreg[4 * q + 1];
        const f4 w2 = wreg[4 * q + 2], w3 = wreg[4 * q + 3];
        acc[0] += a0.x * w0 + a0.y * w1 + a0.z * w2 + a0.w * w3;
        acc[1] += a1.x * w0 + a1.y * w1 + a1.z * w2 + a1.w * w3;
        acc[2] += a2.x * w0 + a2.y * w1 + a2.z * w2 + a2.w * w3;
        acc[3] += a3.x * w0 + a3.y * w1 + a3.z * w2 + a3.w * w3;
      }
    }
    __syncthreads();  // all a_s reads done -> safe to alias-write red2
    // ---- 4. write partials red2[s*264 + out], b128 ----
#pragma unroll
    for (int i = 0; i < 4; ++i)
      *(f4*)&red2[s * 264 + (r0 + i) * 32 + cb] = acc[i];
    __syncthreads();
    // ---- 5. finalize: 256 threads, sum 32 partials, bias+act, store ----
    if (tid < 256) {
      float sum = 0.f;
#pragma unroll
      for (int z = 0; z < 32; ++z) sum += red2[z * 264 + tid];
      if (p == 0) {
        float v = sum + xpre;
        llc_store(slotw + fyi, LRELU(v));
      } else if (p < 3) {
        float v = sum + b_h[(p - 1) * U + fu];
        llc_store(slotw + fyi, LRELU(v));
      } else {
        float yn = ypre + sum + b_out[fu];  // ybuf prefetched at phase start
        ybuf[fyi] = yn;
        llc_store(slotw + fyi, yn);  // y is next p0's A
        yout = yn;                   // out[] store deferred past flag post
        oidx = ((size_t)frow * T + t) * U + fu;
        do_out = 1;
      }
    }
    // ---- 6. drain: exchange stores at LLC before the flag post ----
    asm volatile("" ::: "memory");
    __builtin_amdgcn_s_waitcnt(0);
    __syncthreads();
    // ---- 7. W prefetch for P+1 (issued BEFORE the flag post so the L2/HBM
    //         W traffic overlaps post + poll + A-stage of the next phase) ----
    if (P < 4 * T - 1) {
      const float* wp = wbase(P + 1);
#pragma unroll
      for (int j = 0; j < 32; ++j) wreg[j] = *(const f4*)(wp + (size_t)j * U);
    }
    // ---- 8. release: per-producer flag store (no RMW serialization) ----
    if (tid == 0) llc_flag_store(myflag, (unsigned)(P + 1));
    // ---- 9. deferred p3 out-store (HBM ack off the flag critical path;
    //         next phase's waitcnt(0) absorbs it) ----
    if (do_out) out[oidx] = yout;
  }
}

extern "C" void kernel_launch(void* const* d_in, const int* in_sizes, int n_in,
                              void* d_out, int out_size, void* d_ws,
                              size_t ws_size, hipStream_t stream) {
  const int* x = (const int*)d_in[0];
  const float* emb = (const float*)d_in[1];
  const float* w_y = (const float*)d_in[2];
  const float* w_x = (const float*)d_in[3];
  const float* b_in = (const float*)d_in[4];
  const float* w_h = (const float*)d_in[5];
  const float* b_h = (const float*)d_in[6];
  const float* w_out = (const float*)d_in[7];
  const float* b_out = (const float*)d_in[8];
  const float* h0 = (const float*)d_in[9];
  float* out = (float*)d_out;

  // workspace (floats): xproj | slots[2] | ybuf | flags
  float* ws = (float*)d_ws;
  float* xpb = ws;                         // T*B*U
  float* slots = xpb + (size_t)T * B * U;  // 2*BU
  float* ybuf = slots + 2 * (size_t)BU;    // BU
  unsigned* flags = (unsigned*)(ybuf + (size_t)BU);  // 256 uints (512 zeroed)

  k_init<<<256, 256, 0, stream>>>(slots + (size_t)BU, ybuf, h0, flags);
  dim3 g1(256, 16);
  k_xproj<<<g1, 256, 0, stream>>>(x, emb, w_x, b_in, xpb);

  void* args[] = {&xpb,   &w_y, &w_h,   &b_h,  &w_out,
                  &b_out, &out, &slots, &ybuf, &flags};
  hipLaunchCooperativeKernel((void*)k_seq, dim3(256), dim3(512), args, 0u,
                             stream);
}